// Round 3
// baseline (756.452 us; speedup 1.0000x reference)
//
#include <hip/hip_runtime.h>

typedef short short8 __attribute__((ext_vector_type(8)));
typedef short short4v __attribute__((ext_vector_type(4)));
typedef float f32x4 __attribute__((ext_vector_type(4)));
typedef unsigned short ushort_t;

#define DEV_INLINE __device__ __forceinline__

constexpr int NSEQ = 512, NRES = 384, CM = 256, CO = 32, CZ = 128;
constexpr float F_LN_EPS = 1e-5f, F_NORM_EPS = 1e-3f;

// workspace layout (bytes)
constexpr size_t WS_LT   = 0;                                  // [12288][512] bf16
constexpr size_t WS_RT   = WS_LT + (size_t)12288 * 512 * 2;    // [12288][512] bf16
constexpr size_t WS_WT   = WS_RT + (size_t)12288 * 512 * 2;    // [128][1024] bf16
constexpr size_t WS_NORM = WS_WT + (size_t)128 * 1024 * 2;     // [384][384] f32
constexpr size_t WS_PW   = WS_NORM + (size_t)384 * 384 * 4;    // [64][256] bf16 packed proj weights

DEV_INLINE ushort_t f2bf(float x) {
  union { float f; unsigned u; } v; v.f = x;
  unsigned r = v.u + 0x7FFFu + ((v.u >> 16) & 1u);
  return (ushort_t)(r >> 16);
}

DEV_INLINE short8 pack8(float4 a, float4 b) {
  short8 p;
  p[0] = (short)f2bf(a.x); p[1] = (short)f2bf(a.y);
  p[2] = (short)f2bf(a.z); p[3] = (short)f2bf(a.w);
  p[4] = (short)f2bf(b.x); p[5] = (short)f2bf(b.y);
  p[6] = (short)f2bf(b.z); p[7] = (short)f2bf(b.w);
  return p;
}

// async global->LDS, 16B per lane; lds dest = wave-uniform base + lane*16
DEV_INLINE void async16(const void* g, void* l) {
  __builtin_amdgcn_global_load_lds(
      (const __attribute__((address_space(1))) unsigned*)g,
      (__attribute__((address_space(3))) unsigned*)l, 16, 0, 0);
}

// ---------------------------------------------------------------------------
// Kernel: transpose output_w [c][e][f] f32 -> WT[f][ce] bf16
__global__ __launch_bounds__(256) void k_wt(const float* __restrict__ W,
                                            ushort_t* __restrict__ WT) {
  int tid = blockIdx.x * 256 + threadIdx.x;      // 0..131071
  int f = tid >> 10, ce = tid & 1023;
  WT[tid] = f2bf(W[(size_t)ce * CZ + f]);
}

// ---------------------------------------------------------------------------
// Kernel: pack combined projection weights -> PW[64][256] bf16 (frag-linear).
// Row o<32 = left_w[o], row o>=32 = right_w[o-32].
__global__ __launch_bounds__(256) void k_pack(const float* __restrict__ left_w,
                                              const float* __restrict__ right_w,
                                              ushort_t* __restrict__ PW) {
  int id = blockIdx.x * 256 + threadIdx.x;   // 0..2047
  int o = id >> 5, ch = id & 31;             // 64 rows x 32 chunks of 8
  const float* src = (o < 32 ? left_w + (size_t)o * CM
                             : right_w + (size_t)(o - 32) * CM) + ch * 8;
  float4 a = *(const float4*)src, b = *(const float4*)(src + 4);
  *(short8*)&PW[(size_t)o * CM + ch * 8] = pack8(a, b);
}

// ---------------------------------------------------------------------------
// Kernel: norm[b][d] = sum_a mask[a][b]*mask[a][d]
__global__ __launch_bounds__(256) void k_norm(const float* __restrict__ mask,
                                              float* __restrict__ normM) {
  int b = blockIdx.x * 16 + threadIdx.x;
  int d = blockIdx.y * 16 + threadIdx.y;
  float a0 = 0.f, a1 = 0.f, a2 = 0.f, a3 = 0.f;
  for (int a = 0; a < NSEQ; a += 4) {
    a0 += mask[(size_t)(a + 0) * NRES + b] * mask[(size_t)(a + 0) * NRES + d];
    a1 += mask[(size_t)(a + 1) * NRES + b] * mask[(size_t)(a + 1) * NRES + d];
    a2 += mask[(size_t)(a + 2) * NRES + b] * mask[(size_t)(a + 2) * NRES + d];
    a3 += mask[(size_t)(a + 3) * NRES + b] * mask[(size_t)(a + 3) * NRES + d];
  }
  normM[(size_t)b * NRES + d] = (a0 + a1) + (a2 + a3);
}

// ---------------------------------------------------------------------------
// Kernel: LayerNorm + left/right projection (v3: instruction-coalesced loads).
// grid = (32 a-chunks, 384 res). 16 rows/block, 16 lanes/row.
// Lane c of a row handles channels {j*64 + c*4 .. +3} for j=0..3 so each load
// instruction covers a contiguous 256B per row-group (4KB per wave instr).
__global__ __launch_bounds__(256) void k_lnproj(
    const float* __restrict__ act, const float* __restrict__ mask,
    const float* __restrict__ ln_w, const float* __restrict__ ln_b,
    const float* __restrict__ left_b, const float* __restrict__ right_b,
    const ushort_t* __restrict__ PW,
    ushort_t* __restrict__ Lt, ushort_t* __restrict__ Rt) {
  __shared__ ushort_t sAct[16 * 256];  // 8 KB: [row a][k], XOR-swizzled 16B chunks

  const int t = threadIdx.x;
  const int a0 = blockIdx.x * 16;
  const int b = blockIdx.y;
  const int r = t >> 4, c = t & 15;  // 16 lanes per row

  const float* rowp = act + ((size_t)(a0 + r) * NRES + b) * CM;
  float4 v[4];
  float s = 0.f, ss = 0.f;
#pragma unroll
  for (int j = 0; j < 4; j++) {
    v[j] = *(const float4*)(rowp + j * 64 + c * 4);   // contiguous per instr
    s += v[j].x + v[j].y + v[j].z + v[j].w;
    ss += v[j].x * v[j].x + v[j].y * v[j].y + v[j].z * v[j].z + v[j].w * v[j].w;
  }
  // 16-lane reduce (lanes of one row are consecutive)
  s += __shfl_xor(s, 1);  s += __shfl_xor(s, 2);
  s += __shfl_xor(s, 4);  s += __shfl_xor(s, 8);
  ss += __shfl_xor(ss, 1); ss += __shfl_xor(ss, 2);
  ss += __shfl_xor(ss, 4); ss += __shfl_xor(ss, 8);
  const float mu = s * (1.f / CM);
  const float rs = rsqrtf(ss * (1.f / CM) - mu * mu + F_LN_EPS);

  // ---- preload B fragments from global (L1/L2-resident, shared by all blocks)
  const int lane = t & 63, w = t >> 6;
  const int q = lane >> 4, ln = lane & 15;
  short8 bfrag[8];
#pragma unroll
  for (int ks = 0; ks < 8; ks++)
    bfrag[ks] = *(const short8*)&PW[(size_t)(w * 16 + ln) * CM + (ks * 4 + q) * 8];

  // ---- normalize + stage act_n (bf16), swizzled
#pragma unroll
  for (int j = 0; j < 4; j++) {
    int cb = j * 64 + c * 4;
    float4 lw = *(const float4*)(ln_w + cb);
    float4 lb = *(const float4*)(ln_b + cb);
    float4 x = v[j];
    short4v p;
    p[0] = (short)f2bf((x.x - mu) * rs * lw.x + lb.x);
    p[1] = (short)f2bf((x.y - mu) * rs * lw.y + lb.y);
    p[2] = (short)f2bf((x.z - mu) * rs * lw.z + lb.z);
    p[3] = (short)f2bf((x.w - mu) * rs * lw.w + lb.w);
    int chunk = j * 8 + (c >> 1);   // 16B chunk index 0..31
    *(short4v*)&sAct[r * 256 + ((chunk ^ (r & 7)) * 8) + (c & 1) * 4] = p;
  }
  __syncthreads();

  // ---- MFMA: C[16 a][64 o], K=256. Wave w computes o-cols 16w..16w+15.
  f32x4 acc = {0, 0, 0, 0};
#pragma unroll
  for (int ks = 0; ks < 8; ks++) {
    int kc = ks * 4 + q;  // 16B-chunk index 0..31
    short8 af = *(const short8*)&sAct[ln * 256 + ((kc ^ (ln & 7)) * 8)];
    acc = __builtin_amdgcn_mfma_f32_16x16x32_bf16(af, bfrag[ks], acc, 0, 0, 0);
  }

  // ---- epilogue: bias, mask, pack 4 consecutive a into one 8B store
  const int o = w * 16 + ln;  // wave-uniform left/right split
  float mk[4];
#pragma unroll
  for (int reg = 0; reg < 4; reg++)
    mk[reg] = mask[(size_t)(a0 + q * 4 + reg) * NRES + b];
  float bias = (o < 32) ? left_b[o] : right_b[o - 32];
  ushort_t* dst = (o < 32) ? (Lt + (size_t)(b * 32 + o) * NSEQ)
                           : (Rt + (size_t)(b * 32 + (o - 32)) * NSEQ);
  short4v pk;
#pragma unroll
  for (int reg = 0; reg < 4; reg++)
    pk[reg] = (short)f2bf((acc[reg] + bias) * mk[reg]);
  *(short4v*)&dst[a0 + q * 4] = pk;
}

// ---------------------------------------------------------------------------
// Fused double-GEMM: per block = 4x4 residue pairs.
// GEMM1: P[128 (b,c)][128 (d,e)] = sum_a Lt * Rt (K=512), LDS-staged.
// GEMM2: out[16 pair][128 f] = P2[16][1024] x WT[128][1024]^T,
//        B-fragments read DIRECTLY from global (L2-resident WT) -> no barriers.
__global__ __launch_bounds__(256, 4) void k_opm(
    const ushort_t* __restrict__ Lt, const ushort_t* __restrict__ Rt,
    const ushort_t* __restrict__ WT, const float* __restrict__ normM,
    const float* __restrict__ out_b, float* __restrict__ out) {
  __shared__ ushort_t smem[16384];   // 32 KB
  ushort_t* sA = smem;               // 16 KB: A tile [128][64]
  ushort_t* sB = smem + 8192;        // 16 KB: B tile [128][64]
  ushort_t* sP = smem;               // 32 KB: P2 [16][1024] (reuses A+B)

  const int t = threadIdx.x, lane = t & 63, w = t >> 6;
  const int q = lane >> 4, ln = lane & 15;
  const int wm = w & 1, wn = w >> 1;           // 2x2 wave grid
  const int m0 = blockIdx.x * 128, n0 = blockIdx.y * 128;
  const int srow8 = lane >> 3, schunk = lane & 7;  // staging lane map

  f32x4 acc1[4][4];
#pragma unroll
  for (int i = 0; i < 4; i++)
#pragma unroll
    for (int j = 0; j < 4; j++) acc1[i][j] = {0, 0, 0, 0};

  // ================= GEMM1: K=512, BK=64 =================
  for (int kt = 0; kt < 8; kt++) {
    __syncthreads();
#pragma unroll
    for (int i = 0; i < 4; i++) {
      int rg = w + i * 4;            // 1KB region 0..15
      int r = rg * 8 + srow8;        // tile row 0..127
      int gc = schunk ^ (r & 7);     // swizzle on global side
      async16(Lt + (size_t)(m0 + r) * NSEQ + kt * 64 + gc * 8, (char*)sA + rg * 1024);
      async16(Rt + (size_t)(n0 + r) * NSEQ + kt * 64 + gc * 8, (char*)sB + rg * 1024);
    }
    __syncthreads();
#pragma unroll
    for (int ks = 0; ks < 2; ks++) {
      int kc = ks * 4 + q;  // chunk within row, 0..7
      short8 af[4], bf[4];
#pragma unroll
      for (int tm = 0; tm < 4; tm++) {
        int rr = wm * 64 + tm * 16 + ln;
        af[tm] = *(const short8*)&sA[rr * 64 + ((kc ^ (rr & 7)) * 8)];
      }
#pragma unroll
      for (int tn = 0; tn < 4; tn++) {
        int rr = wn * 64 + tn * 16 + ln;
        bf[tn] = *(const short8*)&sB[rr * 64 + ((kc ^ (rr & 7)) * 8)];
      }
#pragma unroll
      for (int tm = 0; tm < 4; tm++)
#pragma unroll
        for (int tn = 0; tn < 4; tn++)
          acc1[tm][tn] =
              __builtin_amdgcn_mfma_f32_16x16x32_bf16(af[tm], bf[tn], acc1[tm][tn], 0, 0, 0);
    }
  }

  // ============ P -> LDS bf16, layout [pair][ce] swizzled ============
  __syncthreads();
#pragma unroll
  for (int tm = 0; tm < 4; tm++) {
#pragma unroll
    for (int tn = 0; tn < 4; tn++) {
      int pair = (wm * 2 + (tm >> 1)) * 4 + (wn * 2 + (tn >> 1));
      int e = (tn & 1) * 16 + ln;
#pragma unroll
      for (int reg = 0; reg < 4; reg++) {
        int c = (tm & 1) * 16 + q * 4 + reg;
        int ce = c * 32 + e;
        int pos = (ce >> 3) ^ (pair & 7);
        sP[pair * 1024 + pos * 8 + (ce & 7)] = f2bf(acc1[tm][tn][reg]);
      }
    }
  }
  __syncthreads();

  // ================= GEMM2: K=1024, barrier-free =================
  // B-frags straight from global WT (L2-resident, shared across all blocks).
  f32x4 acc2[2] = {{0, 0, 0, 0}, {0, 0, 0, 0}};
  const ushort_t* wb0 = WT + (size_t)(w * 32 + ln) * 1024 + q * 8;
  const ushort_t* wb1 = wb0 + (size_t)16 * 1024;
#pragma unroll
  for (int kt = 0; kt < 16; kt++) {
#pragma unroll
    for (int ks = 0; ks < 2; ks++) {
      int pchunk = kt * 8 + ks * 4 + q;  // P2 chunk 0..127
      short8 af = *(const short8*)&sP[ln * 1024 + ((pchunk ^ (ln & 7)) * 8)];
      short8 b0 = *(const short8*)(wb0 + kt * 64 + ks * 32);
      short8 b1 = *(const short8*)(wb1 + kt * 64 + ks * 32);
      acc2[0] = __builtin_amdgcn_mfma_f32_16x16x32_bf16(af, b0, acc2[0], 0, 0, 0);
      acc2[1] = __builtin_amdgcn_mfma_f32_16x16x32_bf16(af, b1, acc2[1], 0, 0, 0);
    }
  }

  // ================= epilogue =================
  const int b = blockIdx.x * 4 + q;  // pair = q*4+reg -> bb=q, dd=reg
#pragma unroll
  for (int reg = 0; reg < 4; reg++) {
    int d = blockIdx.y * 4 + reg;
    float inv = 1.f / (F_NORM_EPS + normM[(size_t)b * NRES + d]);
#pragma unroll
    for (int tn = 0; tn < 2; tn++) {
      int f = w * 32 + tn * 16 + ln;
      out[((size_t)b * NRES + d) * CZ + f] = (acc2[tn][reg] + out_b[f]) * inv;
    }
  }
}

// ---------------------------------------------------------------------------
extern "C" void kernel_launch(void* const* d_in, const int* in_sizes, int n_in,
                              void* d_out, int out_size, void* d_ws, size_t ws_size,
                              hipStream_t stream) {
  (void)in_sizes; (void)n_in; (void)out_size; (void)ws_size;
  const float* act      = (const float*)d_in[0];
  const float* mask     = (const float*)d_in[1];
  const float* ln_w     = (const float*)d_in[2];
  const float* ln_b     = (const float*)d_in[3];
  const float* left_w   = (const float*)d_in[4];
  const float* left_b   = (const float*)d_in[5];
  const float* right_w  = (const float*)d_in[6];
  const float* right_b  = (const float*)d_in[7];
  const float* output_w = (const float*)d_in[8];
  const float* output_b = (const float*)d_in[9];
  float* out = (float*)d_out;

  char* ws = (char*)d_ws;
  ushort_t* Lt = (ushort_t*)(ws + WS_LT);
  ushort_t* Rt = (ushort_t*)(ws + WS_RT);
  ushort_t* WT = (ushort_t*)(ws + WS_WT);
  float* normM = (float*)(ws + WS_NORM);
  ushort_t* PW = (ushort_t*)(ws + WS_PW);

  hipLaunchKernelGGL(k_pack, dim3(8), dim3(256), 0, stream, left_w, right_w, PW);
  hipLaunchKernelGGL(k_wt, dim3(512), dim3(256), 0, stream, output_w, WT);
  hipLaunchKernelGGL(k_norm, dim3(24, 24), dim3(16, 16), 0, stream, mask, normM);
  hipLaunchKernelGGL(k_lnproj, dim3(32, 384), dim3(256), 0, stream, act, mask,
                     ln_w, ln_b, left_b, right_b, PW, Lt, Rt);
  hipLaunchKernelGGL(k_opm, dim3(96, 96), dim3(256), 0, stream, Lt, Rt, WT,
                     normM, output_b, out);
}

// Round 4
// 635.592 us; speedup vs baseline: 1.1902x; 1.1902x over previous
//
#include <hip/hip_runtime.h>

typedef short short8 __attribute__((ext_vector_type(8)));
typedef short short4v __attribute__((ext_vector_type(4)));
typedef float f32x4 __attribute__((ext_vector_type(4)));
typedef unsigned short ushort_t;

#define DEV_INLINE __device__ __forceinline__

constexpr int NSEQ = 512, NRES = 384, CM = 256, CO = 32, CZ = 128;
constexpr float F_LN_EPS = 1e-5f, F_NORM_EPS = 1e-3f;

// workspace layout (bytes)
constexpr size_t WS_LT   = 0;                                  // [12288][512] bf16
constexpr size_t WS_RT   = WS_LT + (size_t)12288 * 512 * 2;    // [12288][512] bf16
constexpr size_t WS_WT   = WS_RT + (size_t)12288 * 512 * 2;    // [128][1024] bf16 (ec-order)
constexpr size_t WS_NORM = WS_WT + (size_t)128 * 1024 * 2;     // [384][384] f32
constexpr size_t WS_PW   = WS_NORM + (size_t)384 * 384 * 4;    // [64][256] bf16
constexpr size_t WS_MT   = WS_PW + (size_t)64 * 256 * 2;       // [384][512] f32 mask^T

DEV_INLINE ushort_t f2bf(float x) {
  union { float f; unsigned u; } v; v.f = x;
  unsigned r = v.u + 0x7FFFu + ((v.u >> 16) & 1u);
  return (ushort_t)(r >> 16);
}

DEV_INLINE short8 pack8(float4 a, float4 b) {
  short8 p;
  p[0] = (short)f2bf(a.x); p[1] = (short)f2bf(a.y);
  p[2] = (short)f2bf(a.z); p[3] = (short)f2bf(a.w);
  p[4] = (short)f2bf(b.x); p[5] = (short)f2bf(b.y);
  p[6] = (short)f2bf(b.z); p[7] = (short)f2bf(b.w);
  return p;
}

// async global->LDS, 16B per lane; lds dest = wave-uniform base + lane*16
DEV_INLINE void async16(const void* g, void* l) {
  __builtin_amdgcn_global_load_lds(
      (const __attribute__((address_space(1))) unsigned*)g,
      (__attribute__((address_space(3))) unsigned*)l, 16, 0, 0);
}

// ---------------------------------------------------------------------------
// Kernel: output_w [c][e][f] f32 -> WT2[f][e*32+c] bf16 (coalesced read over f)
__global__ __launch_bounds__(256) void k_wt(const float* __restrict__ W,
                                            ushort_t* __restrict__ WT2) {
  int tid = blockIdx.x * 256 + threadIdx.x;      // 0..131071
  int f = tid & 127, ce = tid >> 7;              // lanes sweep f -> coalesced read
  int c = ce >> 5, e = ce & 31;
  WT2[(size_t)f * 1024 + e * 32 + c] = f2bf(W[(size_t)ce * CZ + f]);
}

// ---------------------------------------------------------------------------
// Kernel: pack combined projection weights -> PW[64][256] bf16 (frag-linear).
__global__ __launch_bounds__(256) void k_pack(const float* __restrict__ left_w,
                                              const float* __restrict__ right_w,
                                              ushort_t* __restrict__ PW) {
  int id = blockIdx.x * 256 + threadIdx.x;   // 0..2047
  int o = id >> 5, ch = id & 31;             // 64 rows x 32 chunks of 8
  const float* src = (o < 32 ? left_w + (size_t)o * CM
                             : right_w + (size_t)(o - 32) * CM) + ch * 8;
  float4 a = *(const float4*)src, b = *(const float4*)(src + 4);
  *(short8*)&PW[(size_t)o * CM + ch * 8] = pack8(a, b);
}

// ---------------------------------------------------------------------------
// Kernel: mask[a][b] -> maskT[b][a] f32
__global__ __launch_bounds__(256) void k_mt(const float* __restrict__ mask,
                                            float* __restrict__ maskT) {
  int tid = blockIdx.x * 256 + threadIdx.x;  // 0..196607
  int a = tid % NSEQ, b = tid / NSEQ;
  maskT[(size_t)b * NSEQ + a] = mask[(size_t)a * NRES + b];
}

// ---------------------------------------------------------------------------
// Kernel: norm[b][d] = dot(maskT[b], maskT[d]) — contiguous float4 streams.
__global__ __launch_bounds__(256) void k_norm(const float* __restrict__ maskT,
                                              float* __restrict__ normM) {
  int b = blockIdx.x * 16 + threadIdx.x;
  int d = blockIdx.y * 16 + threadIdx.y;
  const float4* rb = (const float4*)(maskT + (size_t)b * NSEQ);
  const float4* rd = (const float4*)(maskT + (size_t)d * NSEQ);
  float a0 = 0.f, a1 = 0.f, a2 = 0.f, a3 = 0.f;
#pragma unroll 4
  for (int j = 0; j < 128; j += 4) {
    float4 x0 = rb[j], y0 = rd[j];
    float4 x1 = rb[j + 1], y1 = rd[j + 1];
    float4 x2 = rb[j + 2], y2 = rd[j + 2];
    float4 x3 = rb[j + 3], y3 = rd[j + 3];
    a0 += x0.x * y0.x + x0.y * y0.y + x0.z * y0.z + x0.w * y0.w;
    a1 += x1.x * y1.x + x1.y * y1.y + x1.z * y1.z + x1.w * y1.w;
    a2 += x2.x * y2.x + x2.y * y2.y + x2.z * y2.z + x2.w * y2.w;
    a3 += x3.x * y3.x + x3.y * y3.y + x3.z * y3.z + x3.w * y3.w;
  }
  normM[(size_t)b * NRES + d] = (a0 + a1) + (a2 + a3);
}

// ---------------------------------------------------------------------------
// Kernel: LayerNorm + left/right projection (v3, unchanged from R2).
__global__ __launch_bounds__(256) void k_lnproj(
    const float* __restrict__ act, const float* __restrict__ mask,
    const float* __restrict__ ln_w, const float* __restrict__ ln_b,
    const float* __restrict__ left_b, const float* __restrict__ right_b,
    const ushort_t* __restrict__ PW,
    ushort_t* __restrict__ Lt, ushort_t* __restrict__ Rt) {
  __shared__ ushort_t sAct[16 * 256];  // 8 KB

  const int t = threadIdx.x;
  const int a0 = blockIdx.x * 16;
  const int b = blockIdx.y;
  const int r = t >> 4, c = t & 15;

  const float* rowp = act + ((size_t)(a0 + r) * NRES + b) * CM;
  float4 v[4];
  float s = 0.f, ss = 0.f;
#pragma unroll
  for (int j = 0; j < 4; j++) {
    v[j] = *(const float4*)(rowp + j * 64 + c * 4);
    s += v[j].x + v[j].y + v[j].z + v[j].w;
    ss += v[j].x * v[j].x + v[j].y * v[j].y + v[j].z * v[j].z + v[j].w * v[j].w;
  }
  s += __shfl_xor(s, 1);  s += __shfl_xor(s, 2);
  s += __shfl_xor(s, 4);  s += __shfl_xor(s, 8);
  ss += __shfl_xor(ss, 1); ss += __shfl_xor(ss, 2);
  ss += __shfl_xor(ss, 4); ss += __shfl_xor(ss, 8);
  const float mu = s * (1.f / CM);
  const float rs = rsqrtf(ss * (1.f / CM) - mu * mu + F_LN_EPS);

  const int lane = t & 63, w = t >> 6;
  const int q = lane >> 4, ln = lane & 15;
  short8 bfrag[8];
#pragma unroll
  for (int ks = 0; ks < 8; ks++)
    bfrag[ks] = *(const short8*)&PW[(size_t)(w * 16 + ln) * CM + (ks * 4 + q) * 8];

#pragma unroll
  for (int j = 0; j < 4; j++) {
    int cb = j * 64 + c * 4;
    float4 lw = *(const float4*)(ln_w + cb);
    float4 lb = *(const float4*)(ln_b + cb);
    float4 x = v[j];
    short4v p;
    p[0] = (short)f2bf((x.x - mu) * rs * lw.x + lb.x);
    p[1] = (short)f2bf((x.y - mu) * rs * lw.y + lb.y);
    p[2] = (short)f2bf((x.z - mu) * rs * lw.z + lb.z);
    p[3] = (short)f2bf((x.w - mu) * rs * lw.w + lb.w);
    int chunk = j * 8 + (c >> 1);
    *(short4v*)&sAct[r * 256 + ((chunk ^ (r & 7)) * 8) + (c & 1) * 4] = p;
  }
  __syncthreads();

  f32x4 acc = {0, 0, 0, 0};
#pragma unroll
  for (int ks = 0; ks < 8; ks++) {
    int kc = ks * 4 + q;
    short8 af = *(const short8*)&sAct[ln * 256 + ((kc ^ (ln & 7)) * 8)];
    acc = __builtin_amdgcn_mfma_f32_16x16x32_bf16(af, bfrag[ks], acc, 0, 0, 0);
  }

  const int o = w * 16 + ln;
  float mk[4];
#pragma unroll
  for (int reg = 0; reg < 4; reg++)
    mk[reg] = mask[(size_t)(a0 + q * 4 + reg) * NRES + b];
  float bias = (o < 32) ? left_b[o] : right_b[o - 32];
  ushort_t* dst = (o < 32) ? (Lt + (size_t)(b * 32 + o) * NSEQ)
                           : (Rt + (size_t)(b * 32 + (o - 32)) * NSEQ);
  short4v pk;
#pragma unroll
  for (int reg = 0; reg < 4; reg++)
    pk[reg] = (short)f2bf((acc[reg] + bias) * mk[reg]);
  *(short4v*)&dst[a0 + q * 4] = pk;
}

// ---------------------------------------------------------------------------
// Fused double-GEMM (R1 structure + ec-ordered P with b64 writes).
// GEMM1: P[128 (b,c)][128 (d,e)] = sum_a Lt * Rt (K=512), LDS-staged.
// GEMM2: out[16 pair][128 f] = P2[16][1024 ec] x WT2[128][1024 ec]^T, LDS-staged.
__global__ __launch_bounds__(256, 3) void k_opm(
    const ushort_t* __restrict__ Lt, const ushort_t* __restrict__ Rt,
    const ushort_t* __restrict__ WT2, const float* __restrict__ normM,
    const float* __restrict__ out_b, float* __restrict__ out) {
  __shared__ ushort_t smem[24576];   // 48 KB
  ushort_t* sA = smem;               // 16 KB: A tile [128][64]
  ushort_t* sB = smem + 8192;        // 16 KB: B tile [128][64]
  ushort_t* sP = smem;               // 32 KB: P2 [16][1024 ec] (reuses A+B)
  ushort_t* sW = smem + 16384;       // 16 KB: W tile [128][64]

  const int t = threadIdx.x, lane = t & 63, w = t >> 6;
  const int q = lane >> 4, ln = lane & 15;
  const int wm = w & 1, wn = w >> 1;           // 2x2 wave grid
  const int m0 = blockIdx.x * 128, n0 = blockIdx.y * 128;
  const int srow8 = lane >> 3, schunk = lane & 7;  // staging lane map

  f32x4 acc1[4][4];
#pragma unroll
  for (int i = 0; i < 4; i++)
#pragma unroll
    for (int j = 0; j < 4; j++) acc1[i][j] = {0, 0, 0, 0};

  // ================= GEMM1: K=512, BK=64 =================
  for (int kt = 0; kt < 8; kt++) {
    __syncthreads();
#pragma unroll
    for (int i = 0; i < 4; i++) {
      int rg = w + i * 4;            // 1KB region 0..15
      int r = rg * 8 + srow8;        // tile row 0..127
      int gc = schunk ^ (r & 7);     // swizzle on global side
      async16(Lt + (size_t)(m0 + r) * NSEQ + kt * 64 + gc * 8, (char*)sA + rg * 1024);
      async16(Rt + (size_t)(n0 + r) * NSEQ + kt * 64 + gc * 8, (char*)sB + rg * 1024);
    }
    __syncthreads();
#pragma unroll
    for (int ks = 0; ks < 2; ks++) {
      int kc = ks * 4 + q;  // chunk within row, 0..7
      short8 af[4], bf[4];
#pragma unroll
      for (int tm = 0; tm < 4; tm++) {
        int rr = wm * 64 + tm * 16 + ln;
        af[tm] = *(const short8*)&sA[rr * 64 + ((kc ^ (rr & 7)) * 8)];
      }
#pragma unroll
      for (int tn = 0; tn < 4; tn++) {
        int rr = wn * 64 + tn * 16 + ln;
        bf[tn] = *(const short8*)&sB[rr * 64 + ((kc ^ (rr & 7)) * 8)];
      }
#pragma unroll
      for (int tm = 0; tm < 4; tm++)
#pragma unroll
        for (int tn = 0; tn < 4; tn++)
          acc1[tm][tn] =
              __builtin_amdgcn_mfma_f32_16x16x32_bf16(af[tm], bf[tn], acc1[tm][tn], 0, 0, 0);
    }
  }

  // ===== P -> LDS bf16, layout [pair][e*32+c], b64 writes, XOR-swizzled =====
  __syncthreads();
#pragma unroll
  for (int tm = 0; tm < 4; tm++) {
#pragma unroll
    for (int tn = 0; tn < 4; tn++) {
      int pair = (wm * 2 + (tm >> 1)) * 4 + (wn * 2 + (tn >> 1));
      int e = (tn & 1) * 16 + ln;
      // ec = e*32 + (tm&1)*16 + q*4 + reg; regs are 4 consecutive shorts.
      int chunkIdx = e * 4 + (tm & 1) * 2 + (q >> 1);   // 16B-chunk 0..127
      int pos = chunkIdx ^ (pair & 7);
      short4v pk;
#pragma unroll
      for (int reg = 0; reg < 4; reg++) pk[reg] = (short)f2bf(acc1[tm][tn][reg]);
      *(short4v*)&sP[pair * 1024 + pos * 8 + (q & 1) * 4] = pk;
    }
  }
  __syncthreads();

  // ================= GEMM2: K=1024 (ec-order), BK=64, N=128 =================
  f32x4 acc2[2] = {{0, 0, 0, 0}, {0, 0, 0, 0}};
  for (int kt = 0; kt < 16; kt++) {
    if (kt) __syncthreads();
#pragma unroll
    for (int i = 0; i < 4; i++) {
      int rg = w + i * 4;
      int r = rg * 8 + srow8;        // f row 0..127
      int gc = schunk ^ (r & 7);
      async16(WT2 + (size_t)r * 1024 + kt * 64 + gc * 8, (char*)sW + rg * 1024);
    }
    __syncthreads();
#pragma unroll
    for (int ks = 0; ks < 2; ks++) {
      int pchunk = kt * 8 + ks * 4 + q;  // P2 chunk 0..127
      short8 af = *(const short8*)&sP[ln * 1024 + ((pchunk ^ (ln & 7)) * 8)];
      int kc = ks * 4 + q;
#pragma unroll
      for (int tn = 0; tn < 2; tn++) {
        int fr = w * 32 + tn * 16 + ln;
        short8 bf = *(const short8*)&sW[fr * 64 + ((kc ^ (fr & 7)) * 8)];
        acc2[tn] = __builtin_amdgcn_mfma_f32_16x16x32_bf16(af, bf, acc2[tn], 0, 0, 0);
      }
    }
  }

  // ================= epilogue =================
  const int b = blockIdx.x * 4 + q;  // pair = q*4+reg -> bb=q, dd=reg
#pragma unroll
  for (int reg = 0; reg < 4; reg++) {
    int d = blockIdx.y * 4 + reg;
    float inv = 1.f / (F_NORM_EPS + normM[(size_t)b * NRES + d]);
#pragma unroll
    for (int tn = 0; tn < 2; tn++) {
      int f = w * 32 + tn * 16 + ln;
      out[((size_t)b * NRES + d) * CZ + f] = (acc2[tn][reg] + out_b[f]) * inv;
    }
  }
}

// ---------------------------------------------------------------------------
extern "C" void kernel_launch(void* const* d_in, const int* in_sizes, int n_in,
                              void* d_out, int out_size, void* d_ws, size_t ws_size,
                              hipStream_t stream) {
  (void)in_sizes; (void)n_in; (void)out_size; (void)ws_size;
  const float* act      = (const float*)d_in[0];
  const float* mask     = (const float*)d_in[1];
  const float* ln_w     = (const float*)d_in[2];
  const float* ln_b     = (const float*)d_in[3];
  const float* left_w   = (const float*)d_in[4];
  const float* left_b   = (const float*)d_in[5];
  const float* right_w  = (const float*)d_in[6];
  const float* right_b  = (const float*)d_in[7];
  const float* output_w = (const float*)d_in[8];
  const float* output_b = (const float*)d_in[9];
  float* out = (float*)d_out;

  char* ws = (char*)d_ws;
  ushort_t* Lt = (ushort_t*)(ws + WS_LT);
  ushort_t* Rt = (ushort_t*)(ws + WS_RT);
  ushort_t* WT2 = (ushort_t*)(ws + WS_WT);
  float* normM = (float*)(ws + WS_NORM);
  ushort_t* PW = (ushort_t*)(ws + WS_PW);
  float* maskT = (float*)(ws + WS_MT);

  hipLaunchKernelGGL(k_pack, dim3(8), dim3(256), 0, stream, left_w, right_w, PW);
  hipLaunchKernelGGL(k_wt, dim3(512), dim3(256), 0, stream, output_w, WT2);
  hipLaunchKernelGGL(k_mt, dim3(768), dim3(256), 0, stream, mask, maskT);
  hipLaunchKernelGGL(k_norm, dim3(24, 24), dim3(16, 16), 0, stream, maskT, normM);
  hipLaunchKernelGGL(k_lnproj, dim3(32, 384), dim3(256), 0, stream, act, mask,
                     ln_w, ln_b, left_b, right_b, PW, Lt, Rt);
  hipLaunchKernelGGL(k_opm, dim3(96, 96), dim3(256), 0, stream, Lt, Rt, WT2,
                     normM, output_b, out);
}